// Round 1
// baseline (367.743 us; speedup 1.0000x reference)
//
#include <hip/hip_runtime.h>
#include <math.h>

// Problem constants
#define B_N 65536
#define G_N 6
#define IN_N 512
#define F_N 256
#define O_N 18

// Sort constants
#define NB 256     // histogram blocks (B_N / 256)
#define CHUNK 256

// GEMM tiling (m97-style: 128x128 tile, 4 waves, 16x16x32 bf16 MFMA)
#define BM 128
#define BN 128
#define BK 32
#define MAXT 518   // max grouped row-tiles: 512 + G

typedef __bf16 bf16x8 __attribute__((ext_vector_type(8)));
typedef float f32x4 __attribute__((ext_vector_type(4)));

// ---- workspace layout (bytes) ----
// [0, 6144)            blockcounts int[NB*G]
// [8192, 14336)        blockoff    int[NB*G]
// [16384, 16432)       gstart      int[G..]
// [16448, 16452)       ntiles      int
// [16512, ~22728)      desc        int[MAXT*3] (g, row0, nrows)
// [32768, 1605632)     W1t bf16    [G][F][IN]
// [1605632, 1736704)   W2t bf16    [F][F]
// [2097152, 2359296)   perm        int[B]
// [4194304, 37748736)  H1 bf16     [B][F]
// [37748736, 71303168) HF bf16     [B][F]
#define WS_BC     0
#define WS_BOFF   8192
#define WS_GSTART 16384
#define WS_NTILES 16448
#define WS_DESC   16512
#define WS_W1T    32768
#define WS_W2T    1605632
#define WS_PERM   2097152
#define WS_H1     4194304
#define WS_HF     37748736

__device__ __forceinline__ unsigned short f2bf(float f) {
    union { float f; unsigned u; } a; a.f = f;
    unsigned r = a.u + 0x7fffu + ((a.u >> 16) & 1u);
    return (unsigned short)(r >> 16);
}
__device__ __forceinline__ float bf2f(unsigned short h) {
    union { unsigned u; float f; } a; a.u = ((unsigned)h) << 16;
    return a.f;
}
__device__ __forceinline__ unsigned pack2(float a, float b) {
    return (unsigned)f2bf(a) | ((unsigned)f2bf(b) << 16);
}

// ---------- sort: histogram ----------
__global__ void k_hist(const int* __restrict__ idx, int* __restrict__ bc) {
    __shared__ int cnt[G_N];
    int t = threadIdx.x;
    if (t < G_N) cnt[t] = 0;
    __syncthreads();
    int e = blockIdx.x * CHUNK + t;
    atomicAdd(&cnt[idx[e]], 1);
    __syncthreads();
    if (t < G_N) bc[blockIdx.x * G_N + t] = cnt[t];
}

// ---------- sort: prefix + tile descriptors (single block) ----------
__global__ void k_prefix(const int* __restrict__ bc, int* __restrict__ boff,
                         int* __restrict__ gstart, int* __restrict__ ntiles,
                         int* __restrict__ desc) {
    __shared__ int tot[G_N], st[G_N];
    int t = threadIdx.x;
    if (t < G_N) {
        int s = 0;
        for (int b = 0; b < NB; b++) s += bc[b * G_N + t];
        tot[t] = s;
    }
    __syncthreads();
    if (t == 0) {
        int acc = 0;
        for (int g = 0; g < G_N; g++) { st[g] = acc; acc += tot[g]; }
    }
    __syncthreads();
    if (t < G_N) {
        int run = st[t];
        for (int b = 0; b < NB; b++) { boff[b * G_N + t] = run; run += bc[b * G_N + t]; }
        gstart[t] = st[t];
    }
    if (t == 0) {
        int nt = 0;
        for (int g = 0; g < G_N; g++) {
            int rem = tot[g], r0 = st[g];
            while (rem > 0) {
                int take = rem < BM ? rem : BM;
                desc[nt * 3 + 0] = g; desc[nt * 3 + 1] = r0; desc[nt * 3 + 2] = take;
                nt++; r0 += take; rem -= take;
            }
        }
        *ntiles = nt;
        for (int i = nt; i < MAXT; i++) { desc[i * 3 + 0] = 0; desc[i * 3 + 1] = 0; desc[i * 3 + 2] = 0; }
    }
}

// ---------- sort: stable scatter ----------
__global__ void k_scatter(const int* __restrict__ idx, const int* __restrict__ boff,
                          int* __restrict__ perm) {
    __shared__ int wcnt[4][G_N];
    __shared__ int base[G_N];
    int t = threadIdx.x, w = t >> 6, l = t & 63;
    int e = blockIdx.x * CHUNK + t;
    int g = idx[e];
    int rank = 0;
    for (int gg = 0; gg < G_N; gg++) {
        unsigned long long m = __ballot(g == gg);
        if (g == gg) rank = __popcll(m & ((1ull << l) - 1ull));
        if (l == 0) wcnt[w][gg] = __popcll(m);
    }
    if (t < G_N) base[t] = boff[blockIdx.x * G_N + t];
    __syncthreads();
    int off = base[g] + rank;
    for (int ww = 0; ww < w; ww++) off += wcnt[ww][g];
    perm[off] = e;
}

// ---------- weight transpose+convert: [K][N] f32 -> [N][K] bf16 ----------
__global__ void k_trans(const float* __restrict__ src, unsigned short* __restrict__ dst,
                        int K, int N, long srcStrideZ, long dstStrideZ) {
    __shared__ float tile[32][33];
    const float* s = src + (long)blockIdx.z * srcStrideZ;
    unsigned short* d = dst + (long)blockIdx.z * dstStrideZ;
    int n0 = blockIdx.x * 32, k0 = blockIdx.y * 32;
    int tx = threadIdx.x & 31, ty = threadIdx.x >> 5; // ty in 0..7
    for (int r = 0; r < 32; r += 8)
        tile[ty + r][tx] = s[(long)(k0 + ty + r) * N + n0 + tx];
    __syncthreads();
    for (int r = 0; r < 32; r += 8)
        d[(long)(n0 + ty + r) * K + k0 + tx] = f2bf(tile[tx][ty + r]);
}

// ---------- GEMM1: grouped, gathered A (fp32 state -> bf16), sigmoid epilogue ----------
__global__ __launch_bounds__(256) void k_gemm1(
    const float* __restrict__ state, const unsigned short* __restrict__ w1t,
    const float* __restrict__ b1, const int* __restrict__ perm,
    const int* __restrict__ desc, unsigned short* __restrict__ h1) {
    int td = blockIdx.y;
    int g = desc[td * 3 + 0];
    int row0 = desc[td * 3 + 1];
    int nrows = desc[td * 3 + 2];
    if (nrows == 0) return;
    int nbase_g = blockIdx.x * BN;

    __shared__ unsigned short lA[BM][BK];
    __shared__ unsigned short lB[BN][BK];

    int t = threadIdx.x;
    int ar = t >> 1;            // staging row 0..127
    int ah = (t & 1) * 16;      // staging k-offset 0 or 16
    long srow = -1;
    if (ar < nrows) srow = perm[row0 + ar];

    const unsigned short* wbase = w1t + (long)g * F_N * IN_N + (long)nbase_g * IN_N;

    f32x4 acc[4][4];
#pragma unroll
    for (int i = 0; i < 4; i++)
#pragma unroll
        for (int j = 0; j < 4; j++) acc[i][j] = (f32x4){0.f, 0.f, 0.f, 0.f};

    int w = t >> 6, l = t & 63;
    int wm = (w & 1) * 64, wn = (w >> 1) * 64;
    int lrow = l & 15, q = l >> 4;

    for (int k0 = 0; k0 < IN_N; k0 += BK) {
        // stage A: gathered fp32 -> bf16
        if (srow >= 0) {
            const float* sp = state + srow * IN_N + k0 + ah;
            float4 v0 = *(const float4*)(sp);
            float4 v1 = *(const float4*)(sp + 4);
            float4 v2 = *(const float4*)(sp + 8);
            float4 v3 = *(const float4*)(sp + 12);
            uint4 p0 = { pack2(v0.x, v0.y), pack2(v0.z, v0.w), pack2(v1.x, v1.y), pack2(v1.z, v1.w) };
            uint4 p1 = { pack2(v2.x, v2.y), pack2(v2.z, v2.w), pack2(v3.x, v3.y), pack2(v3.z, v3.w) };
            *(uint4*)&lA[ar][ah] = p0;
            *(uint4*)&lA[ar][ah + 8] = p1;
        } else {
            uint4 z = {0, 0, 0, 0};
            *(uint4*)&lA[ar][ah] = z;
            *(uint4*)&lA[ar][ah + 8] = z;
        }
        // stage B: already bf16, [n][k]
        {
            const unsigned short* sp = wbase + (long)ar * IN_N + k0 + ah;
            *(uint4*)&lB[ar][ah] = *(const uint4*)sp;
            *(uint4*)&lB[ar][ah + 8] = *(const uint4*)(sp + 8);
        }
        __syncthreads();
        bf16x8 af[4], bfv[4];
#pragma unroll
        for (int i = 0; i < 4; i++) af[i] = *reinterpret_cast<const bf16x8*>(&lA[wm + i * 16 + lrow][q * 8]);
#pragma unroll
        for (int j = 0; j < 4; j++) bfv[j] = *reinterpret_cast<const bf16x8*>(&lB[wn + j * 16 + lrow][q * 8]);
#pragma unroll
        for (int i = 0; i < 4; i++)
#pragma unroll
            for (int j = 0; j < 4; j++)
                acc[i][j] = __builtin_amdgcn_mfma_f32_16x16x32_bf16(af[i], bfv[j], acc[i][j], 0, 0, 0);
        __syncthreads();
    }

#pragma unroll
    for (int i = 0; i < 4; i++) {
        int mbase = wm + i * 16 + q * 4;
#pragma unroll
        for (int j = 0; j < 4; j++) {
            int n = nbase_g + wn + j * 16 + lrow;
            float bias = b1[g * F_N + n];
#pragma unroll
            for (int r = 0; r < 4; r++) {
                int m = mbase + r;
                if (m < nrows) {
                    float v = acc[i][j][r] + bias;
                    float s = 1.0f / (1.0f + __expf(-v));
                    h1[(long)(row0 + m) * F_N + n] = f2bf(s);
                }
            }
        }
    }
}

// ---------- GEMM2: H1 @ W2 + b2, relu ----------
__global__ __launch_bounds__(256) void k_gemm2(
    const unsigned short* __restrict__ h1, const unsigned short* __restrict__ w2t,
    const float* __restrict__ b2, unsigned short* __restrict__ hf) {
    int row0 = blockIdx.y * BM;
    int nbase_g = blockIdx.x * BN;

    __shared__ unsigned short lA[BM][BK];
    __shared__ unsigned short lB[BN][BK];

    int t = threadIdx.x;
    int ar = t >> 1;
    int ah = (t & 1) * 16;

    f32x4 acc[4][4];
#pragma unroll
    for (int i = 0; i < 4; i++)
#pragma unroll
        for (int j = 0; j < 4; j++) acc[i][j] = (f32x4){0.f, 0.f, 0.f, 0.f};

    int w = t >> 6, l = t & 63;
    int wm = (w & 1) * 64, wn = (w >> 1) * 64;
    int lrow = l & 15, q = l >> 4;

    for (int k0 = 0; k0 < F_N; k0 += BK) {
        {
            const unsigned short* sp = h1 + (long)(row0 + ar) * F_N + k0 + ah;
            *(uint4*)&lA[ar][ah] = *(const uint4*)sp;
            *(uint4*)&lA[ar][ah + 8] = *(const uint4*)(sp + 8);
        }
        {
            const unsigned short* sp = w2t + (long)(nbase_g + ar) * F_N + k0 + ah;
            *(uint4*)&lB[ar][ah] = *(const uint4*)sp;
            *(uint4*)&lB[ar][ah + 8] = *(const uint4*)(sp + 8);
        }
        __syncthreads();
        bf16x8 af[4], bfv[4];
#pragma unroll
        for (int i = 0; i < 4; i++) af[i] = *reinterpret_cast<const bf16x8*>(&lA[wm + i * 16 + lrow][q * 8]);
#pragma unroll
        for (int j = 0; j < 4; j++) bfv[j] = *reinterpret_cast<const bf16x8*>(&lB[wn + j * 16 + lrow][q * 8]);
#pragma unroll
        for (int i = 0; i < 4; i++)
#pragma unroll
            for (int j = 0; j < 4; j++)
                acc[i][j] = __builtin_amdgcn_mfma_f32_16x16x32_bf16(af[i], bfv[j], acc[i][j], 0, 0, 0);
        __syncthreads();
    }

#pragma unroll
    for (int i = 0; i < 4; i++) {
        int mbase = wm + i * 16 + q * 4;
#pragma unroll
        for (int j = 0; j < 4; j++) {
            int n = nbase_g + wn + j * 16 + lrow;
            float bias = b2[n];
#pragma unroll
            for (int r = 0; r < 4; r++) {
                int m = mbase + r;
                float v = acc[i][j][r] + bias;
                v = fmaxf(v, 0.0f);
                hf[(long)(row0 + m) * F_N + n] = f2bf(v);
            }
        }
    }
}

// ---------- final: out[b] = tanh(dot(hf[b,:], Wq[idx[b],:,action[b]]) + bq[idx[b],action[b]]) ----------
__global__ void k_final(const unsigned short* __restrict__ hf, const float* __restrict__ wq,
                        const float* __restrict__ bqv, const int* __restrict__ idx,
                        const int* __restrict__ action, float* __restrict__ out) {
    int t = threadIdx.x, w = t >> 6, l = t & 63;
    long s = (long)blockIdx.x * 4 + w;
    int g = idx[s], a = action[s];
    const unsigned short* hp = hf + s * F_N + l * 4;
    ushort4 hv = *(const ushort4*)hp;
    const float* wp = wq + ((long)g * F_N + l * 4) * O_N + a;
    float sum = bf2f(hv.x) * wp[0] + bf2f(hv.y) * wp[O_N] +
                bf2f(hv.z) * wp[2 * O_N] + bf2f(hv.w) * wp[3 * O_N];
#pragma unroll
    for (int o = 32; o > 0; o >>= 1) sum += __shfl_down(sum, o, 64);
    if (l == 0) out[s] = tanhf(sum + bqv[g * O_N + a]);
}

extern "C" void kernel_launch(void* const* d_in, const int* in_sizes, int n_in,
                              void* d_out, int out_size, void* d_ws, size_t ws_size,
                              hipStream_t stream) {
    const float* state  = (const float*)d_in[0];
    const int*   action = (const int*)d_in[1];
    const int*   idx    = (const int*)d_in[2];
    const float* W1     = (const float*)d_in[3];
    const float* b1     = (const float*)d_in[4];
    const float* W2     = (const float*)d_in[5];
    const float* b2     = (const float*)d_in[6];
    const float* Wq     = (const float*)d_in[7];
    const float* bq     = (const float*)d_in[8];
    float* out = (float*)d_out;

    char* ws = (char*)d_ws;
    int* bc      = (int*)(ws + WS_BC);
    int* boff    = (int*)(ws + WS_BOFF);
    int* gstart  = (int*)(ws + WS_GSTART);
    int* ntiles  = (int*)(ws + WS_NTILES);
    int* desc    = (int*)(ws + WS_DESC);
    unsigned short* W1t = (unsigned short*)(ws + WS_W1T);
    unsigned short* W2t = (unsigned short*)(ws + WS_W2T);
    int* perm    = (int*)(ws + WS_PERM);
    unsigned short* H1  = (unsigned short*)(ws + WS_H1);
    unsigned short* HF  = (unsigned short*)(ws + WS_HF);

    k_hist<<<NB, CHUNK, 0, stream>>>(idx, bc);
    k_prefix<<<1, 64, 0, stream>>>(bc, boff, gstart, ntiles, desc);
    k_scatter<<<NB, CHUNK, 0, stream>>>(idx, boff, perm);
    k_trans<<<dim3(F_N / 32, IN_N / 32, G_N), 256, 0, stream>>>(W1, W1t, IN_N, F_N,
                                                                (long)IN_N * F_N, (long)F_N * IN_N);
    k_trans<<<dim3(F_N / 32, F_N / 32, 1), 256, 0, stream>>>(W2, W2t, F_N, F_N, 0, 0);
    k_gemm1<<<dim3(F_N / BN, MAXT), 256, 0, stream>>>(state, W1t, b1, perm, desc, H1);
    k_gemm2<<<dim3(F_N / BN, B_N / BM), 256, 0, stream>>>(H1, W2t, b2, HF);
    k_final<<<B_N / 4, 256, 0, stream>>>(HF, Wq, bq, idx, action, out);
}

// Round 2
// 332.857 us; speedup vs baseline: 1.1048x; 1.1048x over previous
//
#include <hip/hip_runtime.h>
#include <math.h>

// Problem constants
#define B_N 65536
#define G_N 6
#define IN_N 512
#define F_N 256
#define O_N 18

// Sort constants
#define NB 256     // histogram blocks (B_N / 256)
#define CHUNK 256

// GEMM tiling (m97-style: 128x128 tile, 4 waves, 16x16x32 bf16 MFMA)
#define BM 128
#define BN 128
#define BK 32
#define MAXT 518   // max grouped row-tiles: 512 + G

typedef __bf16 bf16x8 __attribute__((ext_vector_type(8)));
typedef float f32x4 __attribute__((ext_vector_type(4)));

// ---- workspace layout (bytes) ----
#define WS_BC     0
#define WS_BOFF   8192
#define WS_NTILES 16448
#define WS_DESC   16512
#define WS_W1T    32768
#define WS_W2T    1605632
#define WS_PERM   2097152
#define WS_H1     4194304
#define WS_HF     37748736

__device__ __forceinline__ unsigned short f2bf(float f) {
    union { float f; unsigned u; } a; a.f = f;
    unsigned r = a.u + 0x7fffu + ((a.u >> 16) & 1u);
    return (unsigned short)(r >> 16);
}
__device__ __forceinline__ float bf2f(unsigned short h) {
    union { unsigned u; float f; } a; a.u = ((unsigned)h) << 16;
    return a.f;
}
__device__ __forceinline__ unsigned pack2(float a, float b) {
    return (unsigned)f2bf(a) | ((unsigned)f2bf(b) << 16);
}

// ---------- sort: histogram ----------
__global__ void k_hist(const int* __restrict__ idx, int* __restrict__ bc) {
    __shared__ int cnt[G_N];
    int t = threadIdx.x;
    if (t < G_N) cnt[t] = 0;
    __syncthreads();
    int e = blockIdx.x * CHUNK + t;
    atomicAdd(&cnt[idx[e]], 1);
    __syncthreads();
    if (t < G_N) bc[blockIdx.x * G_N + t] = cnt[t];
}

// ---------- sort: prefix + tile descriptors (single block, parallel scan) ----------
__global__ void k_prefix(const int* __restrict__ bc, int* __restrict__ boff,
                         int* __restrict__ ntiles, int* __restrict__ desc) {
    __shared__ int sbc[NB * G_N];   // 6 KB
    __shared__ int tot[G_N], st[G_N];
    __shared__ int tstart[G_N + 1];
    int t = threadIdx.x;
    for (int i = t; i < NB * G_N; i += 256) sbc[i] = bc[i];
    __syncthreads();
    int w = t >> 6, l = t & 63;
    // each wave scans one or two groups: per-lane 4 blocks, shfl inclusive scan
    for (int g = w; g < G_N; g += 4) {
        int v[4]; int s = 0;
#pragma unroll
        for (int j = 0; j < 4; j++) { v[j] = sbc[(l * 4 + j) * G_N + g]; s += v[j]; }
        int inc = s;
#pragma unroll
        for (int o = 1; o < 64; o <<= 1) { int x = __shfl_up(inc, o, 64); if (l >= o) inc += x; }
        int run = inc - s;   // exclusive prefix
        if (l == 63) tot[g] = inc;
#pragma unroll
        for (int j = 0; j < 4; j++) { sbc[(l * 4 + j) * G_N + g] = run; run += v[j]; }
    }
    __syncthreads();
    if (t == 0) {
        int acc = 0;
        for (int g = 0; g < G_N; g++) { st[g] = acc; acc += tot[g]; }
        int nt = 0;
        for (int g = 0; g < G_N; g++) { tstart[g] = nt; nt += (tot[g] + BM - 1) / BM; }
        tstart[G_N] = nt;
        *ntiles = nt;
    }
    __syncthreads();
    for (int i = t; i < NB * G_N; i += 256) boff[i] = sbc[i] + st[i % G_N];
    int nt = tstart[G_N];
    for (int i = t; i < MAXT; i += 256) {
        int gd = 0, r0 = 0, nr = 0;
        if (i < nt) {
            int g = 0;
            while (g < G_N - 1 && i >= tstart[g + 1]) g++;
            int k = i - tstart[g];
            r0 = st[g] + k * BM;
            int rem = tot[g] - k * BM;
            nr = rem < BM ? rem : BM;
            gd = g;
        }
        desc[i * 3 + 0] = gd; desc[i * 3 + 1] = r0; desc[i * 3 + 2] = nr;
    }
}

// ---------- sort: stable scatter ----------
__global__ void k_scatter(const int* __restrict__ idx, const int* __restrict__ boff,
                          int* __restrict__ perm) {
    __shared__ int wcnt[4][G_N];
    __shared__ int base[G_N];
    int t = threadIdx.x, w = t >> 6, l = t & 63;
    int e = blockIdx.x * CHUNK + t;
    int g = idx[e];
    int rank = 0;
    for (int gg = 0; gg < G_N; gg++) {
        unsigned long long m = __ballot(g == gg);
        if (g == gg) rank = __popcll(m & ((1ull << l) - 1ull));
        if (l == 0) wcnt[w][gg] = __popcll(m);
    }
    if (t < G_N) base[t] = boff[blockIdx.x * G_N + t];
    __syncthreads();
    int off = base[g] + rank;
    for (int ww = 0; ww < w; ww++) off += wcnt[ww][g];
    perm[off] = e;
}

// ---------- weight transpose+convert: [K][N] f32 -> [N][K] bf16 ----------
__global__ void k_trans(const float* __restrict__ src, unsigned short* __restrict__ dst,
                        int K, int N, long srcStrideZ, long dstStrideZ) {
    __shared__ float tile[32][33];
    const float* s = src + (long)blockIdx.z * srcStrideZ;
    unsigned short* d = dst + (long)blockIdx.z * dstStrideZ;
    int n0 = blockIdx.x * 32, k0 = blockIdx.y * 32;
    int tx = threadIdx.x & 31, ty = threadIdx.x >> 5; // ty in 0..7
    for (int r = 0; r < 32; r += 8)
        tile[ty + r][tx] = s[(long)(k0 + ty + r) * N + n0 + tx];
    __syncthreads();
    for (int r = 0; r < 32; r += 8)
        d[(long)(n0 + ty + r) * K + k0 + tx] = f2bf(tile[tx][ty + r]);
}

// ---------- GEMM1: grouped, gathered A (fp32 state -> bf16), sigmoid epilogue ----------
// Register-prefetch software pipeline: loads for K-step k+1 issued during MFMA on k.
__global__ __launch_bounds__(256, 3) void k_gemm1(
    const float* __restrict__ state, const unsigned short* __restrict__ w1t,
    const float* __restrict__ b1, const int* __restrict__ perm,
    const int* __restrict__ desc, unsigned short* __restrict__ h1) {
    int td = blockIdx.y;
    int g = desc[td * 3 + 0];
    int row0 = desc[td * 3 + 1];
    int nrows = desc[td * 3 + 2];
    if (nrows == 0) return;
    int nb = blockIdx.x * BN;

    __shared__ unsigned short lA[BM][BK];
    __shared__ unsigned short lB[BN][BK];

    int t = threadIdx.x;
    int ar = t >> 1;            // staging row 0..127
    int ah = (t & 1) * 16;      // staging k-offset (elements)
    long srow = (ar < nrows) ? (long)perm[row0 + ar] : -1;
    const unsigned short* wbase = w1t + ((long)g * F_N + nb + ar) * IN_N + ah;

    float4 a0, a1, a2, a3;
    uint4 bv0, bv1;

    auto LD_A = [&](int k0) {
        if (srow >= 0) {
            const float* sp = state + srow * IN_N + k0 + ah;
            a0 = *(const float4*)(sp);
            a1 = *(const float4*)(sp + 4);
            a2 = *(const float4*)(sp + 8);
            a3 = *(const float4*)(sp + 12);
        } else {
            a0 = make_float4(0.f, 0.f, 0.f, 0.f); a1 = a0; a2 = a0; a3 = a0;
        }
    };
    auto LD_B = [&](int k0) {
        const unsigned short* sp = wbase + k0;
        bv0 = *(const uint4*)(sp);
        bv1 = *(const uint4*)(sp + 8);
    };

    f32x4 acc[4][4];
#pragma unroll
    for (int i = 0; i < 4; i++)
#pragma unroll
        for (int j = 0; j < 4; j++) acc[i][j] = (f32x4){0.f, 0.f, 0.f, 0.f};

    int w = t >> 6, l = t & 63;
    int wm = (w & 1) * 64, wn = (w >> 1) * 64;
    int lrow = l & 15, q = l >> 4;

    LD_A(0); LD_B(0);

    for (int k0 = 0; k0 < IN_N; k0 += BK) {
        uint4 p0 = { pack2(a0.x, a0.y), pack2(a0.z, a0.w), pack2(a1.x, a1.y), pack2(a1.z, a1.w) };
        uint4 p1 = { pack2(a2.x, a2.y), pack2(a2.z, a2.w), pack2(a3.x, a3.y), pack2(a3.z, a3.w) };
        *(uint4*)&lA[ar][ah] = p0;
        *(uint4*)&lA[ar][ah + 8] = p1;
        *(uint4*)&lB[ar][ah] = bv0;
        *(uint4*)&lB[ar][ah + 8] = bv1;
        __syncthreads();
        if (k0 + BK < IN_N) { LD_A(k0 + BK); LD_B(k0 + BK); }
        bf16x8 af[4], bfv[4];
#pragma unroll
        for (int i = 0; i < 4; i++) af[i] = *reinterpret_cast<const bf16x8*>(&lA[wm + i * 16 + lrow][q * 8]);
#pragma unroll
        for (int j = 0; j < 4; j++) bfv[j] = *reinterpret_cast<const bf16x8*>(&lB[wn + j * 16 + lrow][q * 8]);
#pragma unroll
        for (int i = 0; i < 4; i++)
#pragma unroll
            for (int j = 0; j < 4; j++)
                acc[i][j] = __builtin_amdgcn_mfma_f32_16x16x32_bf16(af[i], bfv[j], acc[i][j], 0, 0, 0);
        __syncthreads();
    }

#pragma unroll
    for (int i = 0; i < 4; i++) {
        int mbase = wm + i * 16 + q * 4;
#pragma unroll
        for (int j = 0; j < 4; j++) {
            int n = nb + wn + j * 16 + lrow;
            float bias = b1[g * F_N + n];
#pragma unroll
            for (int r = 0; r < 4; r++) {
                int m = mbase + r;
                if (m < nrows) {
                    float v = acc[i][j][r] + bias;
                    float s = 1.0f / (1.0f + __expf(-v));
                    h1[(long)(row0 + m) * F_N + n] = f2bf(s);
                }
            }
        }
    }
}

// ---------- GEMM2: H1 @ W2 + b2, relu, register-prefetch pipeline ----------
__global__ __launch_bounds__(256, 3) void k_gemm2(
    const unsigned short* __restrict__ h1, const unsigned short* __restrict__ w2t,
    const float* __restrict__ b2, unsigned short* __restrict__ hf) {
    int row0 = blockIdx.y * BM;
    int nb = blockIdx.x * BN;

    __shared__ unsigned short lA[BM][BK];
    __shared__ unsigned short lB[BN][BK];

    int t = threadIdx.x;
    int ar = t >> 1;
    int ah = (t & 1) * 16;

    const unsigned short* abase = h1 + (long)(row0 + ar) * F_N + ah;
    const unsigned short* bbase = w2t + (long)(nb + ar) * F_N + ah;

    uint4 av0, av1, bv0, bv1;
    auto LD = [&](int k0) {
        av0 = *(const uint4*)(abase + k0);
        av1 = *(const uint4*)(abase + k0 + 8);
        bv0 = *(const uint4*)(bbase + k0);
        bv1 = *(const uint4*)(bbase + k0 + 8);
    };

    f32x4 acc[4][4];
#pragma unroll
    for (int i = 0; i < 4; i++)
#pragma unroll
        for (int j = 0; j < 4; j++) acc[i][j] = (f32x4){0.f, 0.f, 0.f, 0.f};

    int w = t >> 6, l = t & 63;
    int wm = (w & 1) * 64, wn = (w >> 1) * 64;
    int lrow = l & 15, q = l >> 4;

    LD(0);

    for (int k0 = 0; k0 < F_N; k0 += BK) {
        *(uint4*)&lA[ar][ah] = av0;
        *(uint4*)&lA[ar][ah + 8] = av1;
        *(uint4*)&lB[ar][ah] = bv0;
        *(uint4*)&lB[ar][ah + 8] = bv1;
        __syncthreads();
        if (k0 + BK < F_N) LD(k0 + BK);
        bf16x8 af[4], bfv[4];
#pragma unroll
        for (int i = 0; i < 4; i++) af[i] = *reinterpret_cast<const bf16x8*>(&lA[wm + i * 16 + lrow][q * 8]);
#pragma unroll
        for (int j = 0; j < 4; j++) bfv[j] = *reinterpret_cast<const bf16x8*>(&lB[wn + j * 16 + lrow][q * 8]);
#pragma unroll
        for (int i = 0; i < 4; i++)
#pragma unroll
            for (int j = 0; j < 4; j++)
                acc[i][j] = __builtin_amdgcn_mfma_f32_16x16x32_bf16(af[i], bfv[j], acc[i][j], 0, 0, 0);
        __syncthreads();
    }

#pragma unroll
    for (int i = 0; i < 4; i++) {
        int mbase = wm + i * 16 + q * 4;
#pragma unroll
        for (int j = 0; j < 4; j++) {
            int n = nb + wn + j * 16 + lrow;
            float bias = b2[n];
#pragma unroll
            for (int r = 0; r < 4; r++) {
                int m = mbase + r;
                float v = acc[i][j][r] + bias;
                v = fmaxf(v, 0.0f);
                hf[(long)(row0 + m) * F_N + n] = f2bf(v);
            }
        }
    }
}

// ---------- final: out[b] = tanh(dot(hf[b,:], Wq[idx[b],:,action[b]]) + bq[idx[b],action[b]]) ----------
__global__ void k_final(const unsigned short* __restrict__ hf, const float* __restrict__ wq,
                        const float* __restrict__ bqv, const int* __restrict__ idx,
                        const int* __restrict__ action, float* __restrict__ out) {
    int t = threadIdx.x, w = t >> 6, l = t & 63;
    long s = (long)blockIdx.x * 4 + w;
    int g = idx[s], a = action[s];
    const unsigned short* hp = hf + s * F_N + l * 4;
    ushort4 hv = *(const ushort4*)hp;
    const float* wp = wq + ((long)g * F_N + l * 4) * O_N + a;
    float sum = bf2f(hv.x) * wp[0] + bf2f(hv.y) * wp[O_N] +
                bf2f(hv.z) * wp[2 * O_N] + bf2f(hv.w) * wp[3 * O_N];
#pragma unroll
    for (int o = 32; o > 0; o >>= 1) sum += __shfl_down(sum, o, 64);
    if (l == 0) out[s] = tanhf(sum + bqv[g * O_N + a]);
}

extern "C" void kernel_launch(void* const* d_in, const int* in_sizes, int n_in,
                              void* d_out, int out_size, void* d_ws, size_t ws_size,
                              hipStream_t stream) {
    const float* state  = (const float*)d_in[0];
    const int*   action = (const int*)d_in[1];
    const int*   idx    = (const int*)d_in[2];
    const float* W1     = (const float*)d_in[3];
    const float* b1     = (const float*)d_in[4];
    const float* W2     = (const float*)d_in[5];
    const float* b2     = (const float*)d_in[6];
    const float* Wq     = (const float*)d_in[7];
    const float* bq     = (const float*)d_in[8];
    float* out = (float*)d_out;

    char* ws = (char*)d_ws;
    int* bc      = (int*)(ws + WS_BC);
    int* boff    = (int*)(ws + WS_BOFF);
    int* ntiles  = (int*)(ws + WS_NTILES);
    int* desc    = (int*)(ws + WS_DESC);
    unsigned short* W1t = (unsigned short*)(ws + WS_W1T);
    unsigned short* W2t = (unsigned short*)(ws + WS_W2T);
    int* perm    = (int*)(ws + WS_PERM);
    unsigned short* H1  = (unsigned short*)(ws + WS_H1);
    unsigned short* HF  = (unsigned short*)(ws + WS_HF);

    k_hist<<<NB, CHUNK, 0, stream>>>(idx, bc);
    k_prefix<<<1, 256, 0, stream>>>(bc, boff, ntiles, desc);
    k_scatter<<<NB, CHUNK, 0, stream>>>(idx, boff, perm);
    k_trans<<<dim3(F_N / 32, IN_N / 32, G_N), 256, 0, stream>>>(W1, W1t, IN_N, F_N,
                                                                (long)IN_N * F_N, (long)F_N * IN_N);
    k_trans<<<dim3(F_N / 32, F_N / 32, 1), 256, 0, stream>>>(W2, W2t, F_N, F_N, 0, 0);
    k_gemm1<<<dim3(F_N / BN, MAXT), 256, 0, stream>>>(state, W1t, b1, perm, desc, H1);
    k_gemm2<<<dim3(F_N / BN, B_N / BM), 256, 0, stream>>>(H1, W2t, b2, HF);
    k_final<<<B_N / 4, 256, 0, stream>>>(HF, Wq, bq, idx, action, out);
}

// Round 3
// 316.933 us; speedup vs baseline: 1.1603x; 1.0502x over previous
//
#include <hip/hip_runtime.h>
#include <math.h>

// Problem constants
#define B_N 65536
#define G_N 6
#define IN_N 512
#define F_N 256
#define O_N 18

// Sort constants
#define NB 256     // histogram blocks (B_N / 256)
#define CHUNK 256

// GEMM tiling (m97-style: 128x128 tile, 4 waves, 16x16x32 bf16 MFMA)
#define BM 128
#define BN 128
#define BK 32
#define MAXT 518   // max grouped row-tiles: 512 + G

typedef __bf16 bf16x8 __attribute__((ext_vector_type(8)));
typedef float f32x4 __attribute__((ext_vector_type(4)));

// ---- workspace layout (bytes) ----
#define WS_BC     0
#define WS_BOFF   8192
#define WS_NTILES 16448
#define WS_DESC   16512
#define WS_W1T    32768
#define WS_W2T    1605632
#define WS_PERM   2097152
#define WS_H1     4194304
#define WS_HF     37748736

__device__ __forceinline__ unsigned short f2bf(float f) {
    union { float f; unsigned u; } a; a.f = f;
    unsigned r = a.u + 0x7fffu + ((a.u >> 16) & 1u);
    return (unsigned short)(r >> 16);
}
__device__ __forceinline__ float bf2f(unsigned short h) {
    union { unsigned u; float f; } a; a.u = ((unsigned)h) << 16;
    return a.f;
}

// async global->LDS, 16B per lane. LDS dest must be wave-uniform base + lane*16.
__device__ __forceinline__ void gll16(const void* g, void* l) {
    __builtin_amdgcn_global_load_lds(
        (const __attribute__((address_space(1))) void*)g,
        (__attribute__((address_space(3))) void*)l, 16, 0, 0);
}

// 8 fp32 (two float4) -> bf16x8, round-half-up (add 0x8000, take hi16 via v_perm)
__device__ __forceinline__ bf16x8 cvt8(const uint4 u0, const uint4 u1) {
    uint4 r;
    r.x = __builtin_amdgcn_perm(u0.y + 0x8000u, u0.x + 0x8000u, 0x07060302u);
    r.y = __builtin_amdgcn_perm(u0.w + 0x8000u, u0.z + 0x8000u, 0x07060302u);
    r.z = __builtin_amdgcn_perm(u1.y + 0x8000u, u1.x + 0x8000u, 0x07060302u);
    r.w = __builtin_amdgcn_perm(u1.w + 0x8000u, u1.z + 0x8000u, 0x07060302u);
    union { uint4 u; bf16x8 b; } c; c.u = r;
    return c.b;
}

// ---------- sort: histogram ----------
__global__ void k_hist(const int* __restrict__ idx, int* __restrict__ bc) {
    __shared__ int cnt[G_N];
    int t = threadIdx.x;
    if (t < G_N) cnt[t] = 0;
    __syncthreads();
    int e = blockIdx.x * CHUNK + t;
    atomicAdd(&cnt[idx[e]], 1);
    __syncthreads();
    if (t < G_N) bc[blockIdx.x * G_N + t] = cnt[t];
}

// ---------- sort: prefix + tile descriptors (single block, parallel scan) ----------
__global__ void k_prefix(const int* __restrict__ bc, int* __restrict__ boff,
                         int* __restrict__ ntiles, int* __restrict__ desc) {
    __shared__ int sbc[NB * G_N];   // 6 KB
    __shared__ int tot[G_N], st[G_N];
    __shared__ int tstart[G_N + 1];
    int t = threadIdx.x;
    for (int i = t; i < NB * G_N; i += 256) sbc[i] = bc[i];
    __syncthreads();
    int w = t >> 6, l = t & 63;
    for (int g = w; g < G_N; g += 4) {
        int v[4]; int s = 0;
#pragma unroll
        for (int j = 0; j < 4; j++) { v[j] = sbc[(l * 4 + j) * G_N + g]; s += v[j]; }
        int inc = s;
#pragma unroll
        for (int o = 1; o < 64; o <<= 1) { int x = __shfl_up(inc, o, 64); if (l >= o) inc += x; }
        int run = inc - s;   // exclusive prefix
        if (l == 63) tot[g] = inc;
#pragma unroll
        for (int j = 0; j < 4; j++) { sbc[(l * 4 + j) * G_N + g] = run; run += v[j]; }
    }
    __syncthreads();
    if (t == 0) {
        int acc = 0;
        for (int g = 0; g < G_N; g++) { st[g] = acc; acc += tot[g]; }
        int nt = 0;
        for (int g = 0; g < G_N; g++) { tstart[g] = nt; nt += (tot[g] + BM - 1) / BM; }
        tstart[G_N] = nt;
        *ntiles = nt;
    }
    __syncthreads();
    for (int i = t; i < NB * G_N; i += 256) boff[i] = sbc[i] + st[i % G_N];
    int nt = tstart[G_N];
    for (int i = t; i < MAXT; i += 256) {
        int gd = 0, r0 = 0, nr = 0;
        if (i < nt) {
            int g = 0;
            while (g < G_N - 1 && i >= tstart[g + 1]) g++;
            int k = i - tstart[g];
            r0 = st[g] + k * BM;
            int rem = tot[g] - k * BM;
            nr = rem < BM ? rem : BM;
            gd = g;
        }
        desc[i * 3 + 0] = gd; desc[i * 3 + 1] = r0; desc[i * 3 + 2] = nr;
    }
}

// ---------- sort: stable scatter ----------
__global__ void k_scatter(const int* __restrict__ idx, const int* __restrict__ boff,
                          int* __restrict__ perm) {
    __shared__ int wcnt[4][G_N];
    __shared__ int base[G_N];
    int t = threadIdx.x, w = t >> 6, l = t & 63;
    int e = blockIdx.x * CHUNK + t;
    int g = idx[e];
    int rank = 0;
    for (int gg = 0; gg < G_N; gg++) {
        unsigned long long m = __ballot(g == gg);
        if (g == gg) rank = __popcll(m & ((1ull << l) - 1ull));
        if (l == 0) wcnt[w][gg] = __popcll(m);
    }
    if (t < G_N) base[t] = boff[blockIdx.x * G_N + t];
    __syncthreads();
    int off = base[g] + rank;
    for (int ww = 0; ww < w; ww++) off += wcnt[ww][g];
    perm[off] = e;
}

// ---------- weight transpose+convert: [K][N] f32 -> [N][K] bf16 ----------
__global__ void k_trans(const float* __restrict__ src, unsigned short* __restrict__ dst,
                        int K, int N, long srcStrideZ, long dstStrideZ) {
    __shared__ float tile[32][33];
    const float* s = src + (long)blockIdx.z * srcStrideZ;
    unsigned short* d = dst + (long)blockIdx.z * dstStrideZ;
    int n0 = blockIdx.x * 32, k0 = blockIdx.y * 32;
    int tx = threadIdx.x & 31, ty = threadIdx.x >> 5; // ty in 0..7
    for (int r = 0; r < 32; r += 8)
        tile[ty + r][tx] = s[(long)(k0 + ty + r) * N + n0 + tx];
    __syncthreads();
    for (int r = 0; r < 32; r += 8)
        d[(long)(n0 + ty + r) * K + k0 + tx] = f2bf(tile[tx][ty + r]);
}

// ---------- GEMM1: grouped, gathered A (fp32 in LDS via global_load_lds), sigmoid ----------
// LDS swizzles (applied on DMA source side so dest stays lane-contiguous):
//   A (fp32, 8x16B chunks/row): chunk' = chunk ^ (row&7)
//   B (bf16, 4x16B chunks/row): chunk' = (chunk + (row>>1)) & 3
__global__ __launch_bounds__(256, 3) void k_gemm1(
    const float* __restrict__ state, const unsigned short* __restrict__ w1t,
    const float* __restrict__ b1, const int* __restrict__ perm,
    const int* __restrict__ desc, unsigned short* __restrict__ h1) {
    int td = blockIdx.y;
    int g = desc[td * 3 + 0];
    int row0 = desc[td * 3 + 1];
    int nrows = desc[td * 3 + 2];
    if (nrows == 0) return;
    int nb = blockIdx.x * BN;

    __shared__ float lAf[BM][BK];            // 16 KB
    __shared__ unsigned short lB[BN][BK];    // 8 KB

    int t = threadIdx.x;
    int w = t >> 6, l = t & 63;

    // ---- A DMA mapping: round r covers local rows r*32 + w*8 + l/8 ----
    int lrowA = l >> 3;            // 0..7
    int lchkA = l & 7;
    int srcChunkA = lchkA ^ lrowA;      // chunk = chunk' ^ (row&7), row&7 == lrowA
    const float* aptr[4];
    float* adst[4];
#pragma unroll
    for (int r = 0; r < 4; r++) {
        int localRow = r * 32 + w * 8 + lrowA;
        int pr = row0 + localRow; if (pr >= B_N) pr = B_N - 1;
        long srow = perm[pr];
        aptr[r] = state + srow * IN_N + srcChunkA * 4;
        adst[r] = &lAf[0][0] + (long)(r * 32 + w * 8) * BK + l * 4;
    }

    // ---- B DMA mapping: round r covers rows r*64 + w*16 + l/4 ----
    int lrowB = l >> 2;            // 0..15
    int lchkB = l & 3;
    const unsigned short* bptr[2];
    unsigned short* bdst[2];
#pragma unroll
    for (int r = 0; r < 2; r++) {
        int rowB = r * 64 + w * 16 + lrowB;
        int srcChunkB = (lchkB - (rowB >> 1)) & 3;
        bptr[r] = w1t + ((long)g * F_N + nb + rowB) * IN_N + srcChunkB * 8;
        bdst[r] = &lB[0][0] + (long)(r * 64 + w * 16) * BK + l * 8;
    }

    f32x4 acc[4][4];
#pragma unroll
    for (int i = 0; i < 4; i++)
#pragma unroll
        for (int j = 0; j < 4; j++) acc[i][j] = (f32x4){0.f, 0.f, 0.f, 0.f};

    int wm = (w & 1) * 64, wn = (w >> 1) * 64;
    int lrow = l & 15, q = l >> 4;

    // hoisted LDS read addresses (loop-invariant)
    const uint4* aAddr0[4]; const uint4* aAddr1[4];
    const bf16x8* bAddr[4];
#pragma unroll
    for (int i = 0; i < 4; i++) {
        int m = wm + i * 16 + lrow;
        aAddr0[i] = (const uint4*)&lAf[m][((2 * q) ^ (m & 7)) * 4];
        aAddr1[i] = (const uint4*)&lAf[m][((2 * q + 1) ^ (m & 7)) * 4];
    }
#pragma unroll
    for (int j = 0; j < 4; j++) {
        int n = wn + j * 16 + lrow;
        bAddr[j] = (const bf16x8*)&lB[n][((q + (n >> 1)) & 3) * 8];
    }

    for (int k0 = 0; k0 < IN_N; k0 += BK) {
#pragma unroll
        for (int r = 0; r < 4; r++) gll16(aptr[r] + k0, adst[r]);
#pragma unroll
        for (int r = 0; r < 2; r++) gll16(bptr[r] + k0, bdst[r]);
        __syncthreads();   // drains vmcnt -> LDS tiles ready
        bf16x8 af[4], bfv[4];
#pragma unroll
        for (int i = 0; i < 4; i++) af[i] = cvt8(*aAddr0[i], *aAddr1[i]);
#pragma unroll
        for (int j = 0; j < 4; j++) bfv[j] = *bAddr[j];
#pragma unroll
        for (int i = 0; i < 4; i++)
#pragma unroll
            for (int j = 0; j < 4; j++)
                acc[i][j] = __builtin_amdgcn_mfma_f32_16x16x32_bf16(af[i], bfv[j], acc[i][j], 0, 0, 0);
        __syncthreads();   // before overwriting tiles
    }

#pragma unroll
    for (int i = 0; i < 4; i++) {
        int mbase = wm + i * 16 + q * 4;
#pragma unroll
        for (int j = 0; j < 4; j++) {
            int n = nb + wn + j * 16 + lrow;
            float bias = b1[g * F_N + n];
#pragma unroll
            for (int r = 0; r < 4; r++) {
                int m = mbase + r;
                if (m < nrows) {
                    float v = acc[i][j][r] + bias;
                    float s = 1.0f / (1.0f + __expf(-v));
                    h1[(long)(row0 + m) * F_N + n] = f2bf(s);
                }
            }
        }
    }
}

// ---------- GEMM2: H1 @ W2 + b2, relu, global_load_lds staging ----------
__global__ __launch_bounds__(256, 3) void k_gemm2(
    const unsigned short* __restrict__ h1, const unsigned short* __restrict__ w2t,
    const float* __restrict__ b2, unsigned short* __restrict__ hf) {
    int row0 = blockIdx.y * BM;
    int nb = blockIdx.x * BN;

    __shared__ unsigned short lA[BM][BK];    // 8 KB
    __shared__ unsigned short lB[BN][BK];    // 8 KB

    int t = threadIdx.x;
    int w = t >> 6, l = t & 63;
    int lrowB = l >> 2;
    int lchkB = l & 3;

    const unsigned short* aptr[2]; unsigned short* adst[2];
    const unsigned short* bptr[2]; unsigned short* bdst[2];
#pragma unroll
    for (int r = 0; r < 2; r++) {
        int row = r * 64 + w * 16 + lrowB;
        int srcChunk = (lchkB - (row >> 1)) & 3;
        aptr[r] = h1 + (long)(row0 + row) * F_N + srcChunk * 8;
        bptr[r] = w2t + (long)(nb + row) * F_N + srcChunk * 8;
        adst[r] = &lA[0][0] + (long)(r * 64 + w * 16) * BK + l * 8;
        bdst[r] = &lB[0][0] + (long)(r * 64 + w * 16) * BK + l * 8;
    }

    f32x4 acc[4][4];
#pragma unroll
    for (int i = 0; i < 4; i++)
#pragma unroll
        for (int j = 0; j < 4; j++) acc[i][j] = (f32x4){0.f, 0.f, 0.f, 0.f};

    int wm = (w & 1) * 64, wn = (w >> 1) * 64;
    int lrow = l & 15, q = l >> 4;

    const bf16x8* aAddr[4]; const bf16x8* bAddr[4];
#pragma unroll
    for (int i = 0; i < 4; i++) {
        int m = wm + i * 16 + lrow;
        aAddr[i] = (const bf16x8*)&lA[m][((q + (m >> 1)) & 3) * 8];
    }
#pragma unroll
    for (int j = 0; j < 4; j++) {
        int n = wn + j * 16 + lrow;
        bAddr[j] = (const bf16x8*)&lB[n][((q + (n >> 1)) & 3) * 8];
    }

    for (int k0 = 0; k0 < F_N; k0 += BK) {
#pragma unroll
        for (int r = 0; r < 2; r++) { gll16(aptr[r] + k0, adst[r]); gll16(bptr[r] + k0, bdst[r]); }
        __syncthreads();
        bf16x8 af[4], bfv[4];
#pragma unroll
        for (int i = 0; i < 4; i++) af[i] = *aAddr[i];
#pragma unroll
        for (int j = 0; j < 4; j++) bfv[j] = *bAddr[j];
#pragma unroll
        for (int i = 0; i < 4; i++)
#pragma unroll
            for (int j = 0; j < 4; j++)
                acc[i][j] = __builtin_amdgcn_mfma_f32_16x16x32_bf16(af[i], bfv[j], acc[i][j], 0, 0, 0);
        __syncthreads();
    }

#pragma unroll
    for (int i = 0; i < 4; i++) {
        int mbase = wm + i * 16 + q * 4;
#pragma unroll
        for (int j = 0; j < 4; j++) {
            int n = nb + wn + j * 16 + lrow;
            float bias = b2[n];
#pragma unroll
            for (int r = 0; r < 4; r++) {
                int m = mbase + r;
                float v = acc[i][j][r] + bias;
                v = fmaxf(v, 0.0f);
                hf[(long)(row0 + m) * F_N + n] = f2bf(v);
            }
        }
    }
}

// ---------- final ----------
__global__ void k_final(const unsigned short* __restrict__ hf, const float* __restrict__ wq,
                        const float* __restrict__ bqv, const int* __restrict__ idx,
                        const int* __restrict__ action, float* __restrict__ out) {
    int t = threadIdx.x, w = t >> 6, l = t & 63;
    long s = (long)blockIdx.x * 4 + w;
    int g = idx[s], a = action[s];
    const unsigned short* hp = hf + s * F_N + l * 4;
    ushort4 hv = *(const ushort4*)hp;
    const float* wp = wq + ((long)g * F_N + l * 4) * O_N + a;
    float sum = bf2f(hv.x) * wp[0] + bf2f(hv.y) * wp[O_N] +
                bf2f(hv.z) * wp[2 * O_N] + bf2f(hv.w) * wp[3 * O_N];
#pragma unroll
    for (int o = 32; o > 0; o >>= 1) sum += __shfl_down(sum, o, 64);
    if (l == 0) out[s] = tanhf(sum + bqv[g * O_N + a]);
}

extern "C" void kernel_launch(void* const* d_in, const int* in_sizes, int n_in,
                              void* d_out, int out_size, void* d_ws, size_t ws_size,
                              hipStream_t stream) {
    const float* state  = (const float*)d_in[0];
    const int*   action = (const int*)d_in[1];
    const int*   idx    = (const int*)d_in[2];
    const float* W1     = (const float*)d_in[3];
    const float* b1     = (const float*)d_in[4];
    const float* W2     = (const float*)d_in[5];
    const float* b2     = (const float*)d_in[6];
    const float* Wq     = (const float*)d_in[7];
    const float* bq     = (const float*)d_in[8];
    float* out = (float*)d_out;

    char* ws = (char*)d_ws;
    int* bc      = (int*)(ws + WS_BC);
    int* boff    = (int*)(ws + WS_BOFF);
    int* ntiles  = (int*)(ws + WS_NTILES);
    int* desc    = (int*)(ws + WS_DESC);
    unsigned short* W1t = (unsigned short*)(ws + WS_W1T);
    unsigned short* W2t = (unsigned short*)(ws + WS_W2T);
    int* perm    = (int*)(ws + WS_PERM);
    unsigned short* H1  = (unsigned short*)(ws + WS_H1);
    unsigned short* HF  = (unsigned short*)(ws + WS_HF);

    k_hist<<<NB, CHUNK, 0, stream>>>(idx, bc);
    k_prefix<<<1, 256, 0, stream>>>(bc, boff, ntiles, desc);
    k_scatter<<<NB, CHUNK, 0, stream>>>(idx, boff, perm);
    k_trans<<<dim3(F_N / 32, IN_N / 32, G_N), 256, 0, stream>>>(W1, W1t, IN_N, F_N,
                                                                (long)IN_N * F_N, (long)F_N * IN_N);
    k_trans<<<dim3(F_N / 32, F_N / 32, 1), 256, 0, stream>>>(W2, W2t, F_N, F_N, 0, 0);
    k_gemm1<<<dim3(F_N / BN, MAXT), 256, 0, stream>>>(state, W1t, b1, perm, desc, H1);
    k_gemm2<<<dim3(F_N / BN, B_N / BM), 256, 0, stream>>>(H1, W2t, b2, HF);
    k_final<<<B_N / 4, 256, 0, stream>>>(HF, Wq, bq, idx, action, out);
}